// Round 1
// baseline (323.605 us; speedup 1.0000x reference)
//
#include <hip/hip_runtime.h>
#include <math.h>

// ---------------------------------------------------------------------------
// EG-GAT layer, fully fused pipeline:
//   K1 h-proj: h[N,128] = x[N,128] @ W_node (per-head concat columns)
//   K2 hist:   counts[dst]++
//   K3 alloc:  contiguous segment start per node via wave-aggregated cursor
//   K4 scatter: bucket edge ids (+ prefetched src ids) by dst
//   K5 agg:    per-node flash-style online segment softmax + gated aggregate
// ---------------------------------------------------------------------------

// K1: register-blocked GEMM, 256 thr/block, 64 rows/block, 8x4 micro-tile.
// W reads are 8-distinct-address broadcasts (L1-cached, 64KB total W).
__global__ __launch_bounds__(256) void k_hproj(
    const float* __restrict__ x, const float* __restrict__ Wn,
    float* __restrict__ h, int N)
{
    int t  = threadIdx.x;
    int cg = t & 31, rg = t >> 5;
    int c0 = cg * 4;                 // output column group (c = head*16 + d)
    int hh = c0 >> 4, d0 = c0 & 15;
    int r0 = blockIdx.x * 64 + rg * 8;
    const float* wbase = Wn + hh * 2048 + d0;   // W_node[hh][k][d0..d0+3]

    float acc[8][4];
#pragma unroll
    for (int j = 0; j < 8; ++j)
#pragma unroll
        for (int q = 0; q < 4; ++q) acc[j][q] = 0.f;

    int rr[8];
#pragma unroll
    for (int j = 0; j < 8; ++j) { int n = r0 + j; rr[j] = (n < N) ? n : (N - 1); }

    for (int k0 = 0; k0 < 128; k0 += 4) {
        float4 b0 = *(const float4*)(wbase + (k0 + 0) * 16);
        float4 b1 = *(const float4*)(wbase + (k0 + 1) * 16);
        float4 b2 = *(const float4*)(wbase + (k0 + 2) * 16);
        float4 b3 = *(const float4*)(wbase + (k0 + 3) * 16);
#pragma unroll
        for (int j = 0; j < 8; ++j) {
            float4 a = *(const float4*)(x + (size_t)rr[j] * 128 + k0);
            acc[j][0] += a.x * b0.x + a.y * b1.x + a.z * b2.x + a.w * b3.x;
            acc[j][1] += a.x * b0.y + a.y * b1.y + a.z * b2.y + a.w * b3.y;
            acc[j][2] += a.x * b0.z + a.y * b1.z + a.z * b2.z + a.w * b3.z;
            acc[j][3] += a.x * b0.w + a.y * b1.w + a.z * b2.w + a.w * b3.w;
        }
    }
#pragma unroll
    for (int j = 0; j < 8; ++j) {
        int n = r0 + j;
        if (n < N) {
            float4 v = make_float4(acc[j][0], acc[j][1], acc[j][2], acc[j][3]);
            *(float4*)(h + (size_t)n * 128 + c0) = v;
        }
    }
}

// K2: in-degree histogram
__global__ __launch_bounds__(256) void k_hist(
    const int* __restrict__ dst, int* __restrict__ counts, int E)
{
    int e = blockIdx.x * 256 + threadIdx.x;
    if (e < E) atomicAdd(counts + dst[e], 1);
}

// K3: allocate contiguous segment per node. Placement order is irrelevant,
// so a single global cursor (one atomic per WAVE, not per thread) replaces
// a full prefix scan.
__global__ __launch_bounds__(256) void k_alloc(
    const int* __restrict__ counts, int* __restrict__ start,
    int* __restrict__ cursor, int* __restrict__ gcur, int N)
{
    int i = blockIdx.x * 256 + threadIdx.x;
    int lane = threadIdx.x & 63;
    int v = (i < N) ? counts[i] : 0;
    int incl = v;
#pragma unroll
    for (int o = 1; o < 64; o <<= 1) {
        int u = __shfl_up(incl, o);
        if (lane >= o) incl += u;
    }
    int total = __shfl(incl, 63);
    int base = 0;
    if (lane == 63) base = atomicAdd(gcur, total);
    base = __shfl(base, 63);
    int st = base + incl - v;
    if (i < N) { start[i] = st; cursor[i] = st; }
}

// K4: bucket edges by dst; also stash src so K5 avoids a dependent load chain.
__global__ __launch_bounds__(256) void k_scatter(
    const int* __restrict__ src, const int* __restrict__ dst,
    int* __restrict__ cursor, int* __restrict__ s_eid,
    int* __restrict__ s_src, int E)
{
    int e = blockIdx.x * 256 + threadIdx.x;
    if (e < E) {
        int dn = dst[e];
        int pos = atomicAdd(cursor + dn, 1);
        s_eid[pos] = e;
        s_src[pos] = src[e];
    }
}

// K5: one block (128 thr = H*D output columns) per node. Flash-style online
// softmax over the node's in-edge segment, edge-gated message accumulate.
// No LDS, no syncthreads: logit reduce is a 16-lane shfl_xor tree.
__global__ __launch_bounds__(128) void k_agg(
    const float* __restrict__ h, const float* __restrict__ ea,
    const float* __restrict__ We, const int* __restrict__ s_eid,
    const int* __restrict__ s_src, const int* __restrict__ start,
    const int* __restrict__ counts, float* __restrict__ out, int N)
{
    int n = blockIdx.x;
    if (n >= N) return;
    int c = threadIdx.x;            // c = head*16 + d
    int head = c >> 4, d = c & 15;

    // W_edge column for this (head, d): 16 regs, reused every edge
    float w[16];
#pragma unroll
    for (int i = 0; i < 16; ++i) w[i] = We[head * 256 + i * 16 + d];

    float q = h[(size_t)n * 128 + c];
    int deg = counts[n], s0 = start[n];

    float m = -INFINITY, l = 0.f, acc = 0.f;
    for (int j = 0; j < deg; ++j) {
        int eid = s_eid[s0 + j];
        int sn  = s_src[s0 + j];
        float kv = h[(size_t)sn * 128 + c];           // coalesced 512B row
        const float4* e4 = (const float4*)(ea + (size_t)eid * 16);
        float4 a0 = e4[0], a1 = e4[1], a2 = e4[2], a3 = e4[3];
        float ev = a0.x * w[0]  + a0.y * w[1]  + a0.z * w[2]  + a0.w * w[3]
                 + a1.x * w[4]  + a1.y * w[5]  + a1.z * w[6]  + a1.w * w[7]
                 + a2.x * w[8]  + a2.y * w[9]  + a2.z * w[10] + a2.w * w[11]
                 + a3.x * w[12] + a3.y * w[13] + a3.z * w[14] + a3.w * w[15];

        // logit_h = (q.k + sum_d e) * scale : per-lane partial, 16-lane tree
        float part = fmaf(q, kv, ev);
        part += __shfl_xor(part, 1);
        part += __shfl_xor(part, 2);
        part += __shfl_xor(part, 4);
        part += __shfl_xor(part, 8);
        float logit = part * 0.25f;                   // 1/sqrt(D)
        logit = (logit > 0.f) ? logit : 0.2f * logit; // leaky_relu 0.2

        float nm = fmaxf(m, logit);
        float f  = __expf(m - nm);                    // 0 on first edge
        float p  = __expf(logit - nm);
        float sig = 1.f / (1.f + __expf(-ev));
        l   = l * f + p;
        acc = acc * f + p * kv * sig;
        m = nm;
    }
    out[(size_t)n * 128 + c] = acc / (l + 1e-9f);
}

extern "C" void kernel_launch(void* const* d_in, const int* in_sizes, int n_in,
                              void* d_out, int out_size, void* d_ws, size_t ws_size,
                              hipStream_t stream)
{
    const float* x  = (const float*)d_in[0];
    const float* ea = (const float*)d_in[1];
    const float* Wn = (const float*)d_in[2];
    const float* We = (const float*)d_in[3];
    const int*  src = (const int*)d_in[4];
    const int*  dst = (const int*)d_in[5];
    float* out = (float*)d_out;

    int N = in_sizes[0] / 128;   // 50000
    int E = in_sizes[4];         // 800000

    char* ws = (char*)d_ws;
    float* h    = (float*)ws;                                  // N*128 f32
    int* s_eid  = (int*)(ws + (size_t)N * 128 * sizeof(float));
    int* s_src  = s_eid + E;
    int* counts = s_src + E;
    int* gcur   = counts + N;                                  // 1 int
    int* start  = gcur + 1;
    int* cursor = start + N;

    // zero counts + gcur in one shot
    hipMemsetAsync(counts, 0, (size_t)(N + 1) * sizeof(int), stream);

    k_hproj  <<<(N + 63) / 64,   256, 0, stream>>>(x, Wn, h, N);
    k_hist   <<<(E + 255) / 256, 256, 0, stream>>>(dst, counts, E);
    k_alloc  <<<(N + 255) / 256, 256, 0, stream>>>(counts, start, cursor, gcur, N);
    k_scatter<<<(E + 255) / 256, 256, 0, stream>>>(src, dst, cursor, s_eid, s_src, E);
    k_agg    <<<N, 128, 0, stream>>>(h, ea, We, s_eid, s_src, start, counts, out, N);
}